// Round 7
// baseline (6885.435 us; speedup 1.0000x reference)
//
#include <hip/hip_runtime.h>
#include <stdint.h>

typedef unsigned short u16;
typedef unsigned long long u64;
typedef __attribute__((ext_vector_type(8))) short short8;
typedef __attribute__((ext_vector_type(4))) float floatx4;

#define K_IN    4096   // INPUT_SIZE
#define HID     1024   // HIDDEN
#define G4H     4096   // 4*HIDDEN
#define T_STEPS 2048   // WINDOW
#define NWG     128    // scan workgroups; each owns 8 hidden units
#define SPIN_MAX 20000 // watchdog sweeps; then thread runs free (wrong > hung)

__device__ __forceinline__ u16 f2bf(float f) {
  union { float f; unsigned int i; } v; v.f = f;
  unsigned int lsb = (v.i >> 16) & 1u;
  v.i += 0x7fffu + lsb;
  return (u16)(v.i >> 16);
}
// NaN/Inf -> 0 via INTEGER exponent test: immune to fast-math folding.
__device__ __forceinline__ float finz(float x) {
  unsigned b = __float_as_uint(x);
  return ((b & 0x7f800000u) == 0x7f800000u) ? 0.f : x;
}
__device__ __forceinline__ float sigm(float x) {
  x = fminf(30.f, fmaxf(-30.f, finz(x)));
  return 1.0f / (1.0f + __expf(-x));
}
__device__ __forceinline__ float tanh_s(float x) {
  x = fminf(15.f, fmaxf(-15.f, finz(x)));
  float e = __expf(2.0f * x);
  return (e - 1.0f) / (e + 1.0f);
}

// tagged publish: slot s entry = ((s+1)<<32) | f32bits(h). poison 0xAAAAAAAA never matches.
__device__ __forceinline__ void publish_h(u64* hx, int slot, int idx, float h) {
  h = finz(h);
  u64 v = ((u64)(unsigned)(slot + 1) << 32) | (u64)__float_as_uint(h);
  __hip_atomic_store(&hx[(size_t)slot * HID + idx], v,
                     __ATOMIC_RELAXED, __HIP_MEMORY_SCOPE_AGENT);
}

// ---------------------------------------------------------------------------
// Phase 0: f32 -> bf16 conversion
// ---------------------------------------------------------------------------
__global__ __launch_bounds__(256) void cvt_bf16_k(const float* __restrict__ src,
                                                  u16* __restrict__ dst, int n4) {
  int i = blockIdx.x * 256 + threadIdx.x;
  if (i < n4) {
    float4 v = *(const float4*)(src + (size_t)i * 4);
    u16 o0 = f2bf(v.x), o1 = f2bf(v.y), o2 = f2bf(v.z), o3 = f2bf(v.w);
    ushort4 o = {o0, o1, o2, o3};
    *(ushort4*)(dst + (size_t)i * 4) = o;
  }
}

// ---------------------------------------------------------------------------
// Phase 1: xg = inp @ W_ih^T + b_ih (f32 out). 128x128 tile, BK=64, bf16 MFMA.
// ---------------------------------------------------------------------------
__global__ __launch_bounds__(256) void xg_gemm_k(const u16* __restrict__ A,      // [2048,4096] bf16
                                                 const u16* __restrict__ B,      // [4096,4096] bf16
                                                 const float* __restrict__ bias, // [4096] f32
                                                 float* __restrict__ C)          // [2048,4096] f32
{
  __shared__ __align__(16) u16 As[128 * 64];
  __shared__ __align__(16) u16 Bs[128 * 64];
  const int tid  = threadIdx.x;
  const int lane = tid & 63;
  const int quad = lane >> 4;
  const int l16  = lane & 15;
  const int wid  = tid >> 6;
  const int wm   = wid >> 1, wn = wid & 1;
  const int tileM = blockIdx.y * 128;
  const int tileN = blockIdx.x * 128;

  floatx4 acc[4][4];
  #pragma unroll
  for (int mi = 0; mi < 4; ++mi)
    #pragma unroll
    for (int ni = 0; ni < 4; ++ni)
      acc[mi][ni] = (floatx4){0.f, 0.f, 0.f, 0.f};

  for (int k0 = 0; k0 < K_IN; k0 += 64) {
    #pragma unroll
    for (int i = 0; i < 4; ++i) {
      int c = i * 256 + tid;
      int row = c >> 3, col = (c & 7) * 8;
      *(short8*)(As + c * 8) = *(const short8*)(A + (size_t)(tileM + row) * K_IN + k0 + col);
      *(short8*)(Bs + c * 8) = *(const short8*)(B + (size_t)(tileN + row) * K_IN + k0 + col);
    }
    __syncthreads();
    #pragma unroll
    for (int kk = 0; kk < 64; kk += 32) {
      short8 av[4], bv[4];
      #pragma unroll
      for (int mi = 0; mi < 4; ++mi)
        av[mi] = *(const short8*)(As + (wm * 64 + mi * 16 + l16) * 64 + kk + quad * 8);
      #pragma unroll
      for (int ni = 0; ni < 4; ++ni)
        bv[ni] = *(const short8*)(Bs + (wn * 64 + ni * 16 + l16) * 64 + kk + quad * 8);
      #pragma unroll
      for (int mi = 0; mi < 4; ++mi)
        #pragma unroll
        for (int ni = 0; ni < 4; ++ni)
          acc[mi][ni] = __builtin_amdgcn_mfma_f32_16x16x32_bf16(av[mi], bv[ni], acc[mi][ni], 0, 0, 0);
    }
    __syncthreads();
  }
  #pragma unroll
  for (int ni = 0; ni < 4; ++ni) {
    int n = tileN + wn * 64 + ni * 16 + l16;
    float bn = bias[n];
    #pragma unroll
    for (int mi = 0; mi < 4; ++mi) {
      int mbase = tileM + wm * 64 + mi * 16 + quad * 4;
      #pragma unroll
      for (int r = 0; r < 4; ++r)
        C[(size_t)(mbase + r) * G4H + n] = acc[mi][ni][r] + bn;
    }
  }
}

// ---------------------------------------------------------------------------
// Phase 2: persistent scan, BARRIER-FREE inner loop.
// Wave w of block g owns units U0=g*8+2w, U0+1 — ALL 4 gates of each.
//   row[u] = (u&3)*HID + U0 + (u>>2), u=0..7  (i,f,g,o per unit)
// Thread (w,lane) polls h[j*64+lane] j=0..15 straight into registers (no LDS),
// dots 8 rows, 64-lane butterfly, lanes 0/1 compute gates+state, publish.
// ---------------------------------------------------------------------------
__global__ __launch_bounds__(256, 1) void lstm_scan_k(const float* __restrict__ Whh,
                                                      const float* __restrict__ bhh,
                                                      const float* __restrict__ h1,
                                                      const float* __restrict__ c1,
                                                      const float* __restrict__ fcw,
                                                      const float* __restrict__ fcb,
                                                      const float* __restrict__ xg,
                                                      u64* hx,        // [T_STEPS+1][1024]
                                                      float* out)     // [2080] f32
{
  const int g    = blockIdx.x;
  const int tid  = threadIdx.x;
  const int lane = tid & 63;
  const int w    = tid >> 6;
  const int U0   = g * 8 + w * 2;

  __shared__ float h_local[HID];   // used only by final FC (block 0)
  __shared__ float pp[32][8];

  // W_hh rows for this wave's 8 dots -> VGPRs (coalesced 64x4B per (u,j))
  float wreg[8][16];
  #pragma unroll
  for (int u = 0; u < 8; ++u) {
    const size_t row = (size_t)((u & 3) * HID + U0 + (u >> 2));
    #pragma unroll
    for (int j = 0; j < 16; ++j)
      wreg[u][j] = Whh[row * HID + j * 64 + lane];
  }

  float bq[4] = {0.f, 0.f, 0.f, 0.f};
  float c_state = 0.f;
  if (lane < 2) {
    const int U = U0 + lane;
    #pragma unroll
    for (int q = 0; q < 4; ++q) bq[q] = bhh[q * HID + U];
    c_state = c1[U];
    publish_h(hx, 0, U, h1[U]);
  }

  int alive = 1;
  for (int t = 0; t < T_STEPS; ++t) {
    // prefetch xg for the 2 computing lanes (hidden behind the poll)
    float xq[4] = {0.f, 0.f, 0.f, 0.f};
    if (lane < 2) {
      const size_t xb = (size_t)t * G4H + U0 + lane;
      #pragma unroll
      for (int q = 0; q < 4; ++q) xq[q] = finz(xg[xb + q * HID]);
    }

    // register-direct poll of the 16 entries this thread consumes
    float h[16];
    {
      const u64* p = hx + (size_t)t * HID + lane;
      const unsigned tag = (unsigned)(t + 1);
      int got = 0;
      if (alive) {
        int spins = 0;
        for (;;) {
          u64 v[16];
          #pragma unroll
          for (int j = 0; j < 16; ++j)
            v[j] = __hip_atomic_load(&p[j * 64], __ATOMIC_RELAXED, __HIP_MEMORY_SCOPE_AGENT);
          int ok = 1;
          #pragma unroll
          for (int j = 0; j < 16; ++j)
            ok &= ((unsigned)(v[j] >> 32) == tag);
          if (ok) {
            #pragma unroll
            for (int j = 0; j < 16; ++j)
              h[j] = finz(__uint_as_float((unsigned)v[j]));
            got = 1;
            break;
          }
          if (++spins > SPIN_MAX) { alive = 0; break; }
        }
      }
      if (!got) {
        #pragma unroll
        for (int j = 0; j < 16; ++j) h[j] = 0.f;
      }
    }

    // 8 dots over the 16 register h values
    float s[8] = {0.f, 0.f, 0.f, 0.f, 0.f, 0.f, 0.f, 0.f};
    #pragma unroll
    for (int j = 0; j < 16; ++j) {
      #pragma unroll
      for (int u = 0; u < 8; ++u) s[u] = fmaf(wreg[u][j], h[j], s[u]);
    }
    // 64-lane butterfly
    #pragma unroll
    for (int d = 1; d < 64; d <<= 1) {
      #pragma unroll
      for (int u = 0; u < 8; ++u) s[u] += __shfl_xor(s[u], d, 64);
    }

    // lanes 0/1: gates + state + publish (no barriers anywhere)
    if (lane < 2) {
      const int b = lane * 4;
      float gi = s[b + 0] + xq[0] + bq[0];
      float gf = s[b + 1] + xq[1] + bq[1];
      float gg = s[b + 2] + xq[2] + bq[2];
      float go = s[b + 3] + xq[3] + bq[3];
      float iv = sigm(gi), fv = sigm(gf), gv = tanh_s(gg), ov = sigm(go);
      c_state = finz(fv * c_state + iv * gv);
      float hval = ov * tanh_s(c_state);
      publish_h(hx, t + 1, U0 + lane, hval);
      if (t == 1023) {                         // hs[STRIDE-1], cs[STRIDE-1]
        out[32 + U0 + lane]       = finz(hval);
        out[32 + HID + U0 + lane] = finz(c_state);
      }
    }
  }

  // out[0:32] = tanh(h_fin @ fc_w^T + fc_b): block 0 only
  if (g == 0) {
    if (w == 0) {                              // wave 0 gathers h_fin
      const u64* p = hx + (size_t)T_STEPS * HID + lane;
      const unsigned tag = (unsigned)(T_STEPS + 1);
      u64 v[16];
      int got = 0;
      if (alive) {
        int spins = 0;
        for (;;) {
          #pragma unroll
          for (int j = 0; j < 16; ++j)
            v[j] = __hip_atomic_load(&p[j * 64], __ATOMIC_RELAXED, __HIP_MEMORY_SCOPE_AGENT);
          int ok = 1;
          #pragma unroll
          for (int j = 0; j < 16; ++j)
            ok &= ((unsigned)(v[j] >> 32) == tag);
          if (ok) { got = 1; break; }
          if (++spins > SPIN_MAX) break;
        }
      }
      #pragma unroll
      for (int j = 0; j < 16; ++j)
        h_local[j * 64 + lane] = got ? finz(__uint_as_float((unsigned)v[j])) : 0.f;
    }
    __syncthreads();
    const int m = tid >> 3, seg = tid & 7;
    float pacc = 0.f;
    for (int k = seg * 128; k < seg * 128 + 128; ++k)
      pacc = fmaf(fcw[m * HID + k], h_local[k], pacc);
    pp[m][seg] = finz(pacc);
    __syncthreads();
    if (tid < 32) {
      float sum = fcb[tid];
      #pragma unroll
      for (int i = 0; i < 8; ++i) sum += pp[tid][i];
      out[tid] = tanh_s(finz(sum));
    }
  }
}

extern "C" void kernel_launch(void* const* d_in, const int* in_sizes, int n_in,
                              void* d_out, int out_size, void* d_ws, size_t ws_size,
                              hipStream_t stream) {
  const float* inp = (const float*)d_in[0];
  const float* h1  = (const float*)d_in[1];
  const float* c1  = (const float*)d_in[2];
  const float* Wih = (const float*)d_in[3];
  const float* Whh = (const float*)d_in[4];
  const float* bih = (const float*)d_in[5];
  const float* bhh = (const float*)d_in[6];
  const float* fcw = (const float*)d_in[7];
  const float* fcb = (const float*)d_in[8];
  float* out = (float*)d_out;

  const size_t xg_bytes  = (size_t)T_STEPS * G4H * 4;             // 33.5 MB
  const size_t hx_bytes  = (size_t)(T_STEPS + 1) * HID * 8;       // 16.8 MB
  const size_t ab_bytes  = (size_t)T_STEPS * K_IN * 2;            // 16.8 MB
  const size_t wb_bytes  = (size_t)G4H * K_IN * 2;                // 33.5 MB
  if (ws_size < xg_bytes + hx_bytes + ab_bytes + wb_bytes) return;

  float* xg   = (float*)d_ws;
  u64*   hx   = (u64*)((char*)d_ws + xg_bytes);
  u16*   Abf  = (u16*)((char*)d_ws + xg_bytes + hx_bytes);
  u16*   Wbf  = (u16*)((char*)d_ws + xg_bytes + hx_bytes + ab_bytes);

  const int nA4 = T_STEPS * K_IN / 4;
  const int nW4 = G4H * K_IN / 4;
  cvt_bf16_k<<<dim3((nA4 + 255) / 256), 256, 0, stream>>>(inp, Abf, nA4);
  cvt_bf16_k<<<dim3((nW4 + 255) / 256), 256, 0, stream>>>(Wih, Wbf, nW4);
  xg_gemm_k<<<dim3(G4H / 128, T_STEPS / 128), 256, 0, stream>>>(Abf, Wbf, bih, xg);
  lstm_scan_k<<<dim3(NWG), 256, 0, stream>>>(Whh, bhh, h1, c1, fcw, fcb, xg, hx, out);
}

// Round 8
// 4806.132 us; speedup vs baseline: 1.4326x; 1.4326x over previous
//
#include <hip/hip_runtime.h>
#include <stdint.h>

typedef unsigned short u16;
typedef unsigned long long u64;
typedef __attribute__((ext_vector_type(8))) short short8;
typedef __attribute__((ext_vector_type(4))) float floatx4;

#define K_IN    4096   // INPUT_SIZE
#define HID     1024   // HIDDEN
#define G4H     4096   // 4*HIDDEN
#define T_STEPS 2048   // WINDOW
#define NWG     128    // scan workgroups; each owns 8 hidden units
#define SPIN_MAX 60000 // watchdog sweeps; then thread runs free (wrong > hung)

__device__ __forceinline__ u16 f2bf(float f) {
  union { float f; unsigned int i; } v; v.f = f;
  unsigned int lsb = (v.i >> 16) & 1u;
  v.i += 0x7fffu + lsb;
  return (u16)(v.i >> 16);
}
// NaN/Inf -> 0 via INTEGER exponent test: immune to fast-math folding.
__device__ __forceinline__ float finz(float x) {
  unsigned b = __float_as_uint(x);
  return ((b & 0x7f800000u) == 0x7f800000u) ? 0.f : x;
}
__device__ __forceinline__ float sigm(float x) {
  x = fminf(30.f, fmaxf(-30.f, finz(x)));
  return 1.0f / (1.0f + __expf(-x));
}
__device__ __forceinline__ float tanh_s(float x) {
  x = fminf(15.f, fmaxf(-15.f, finz(x)));
  float e = __expf(2.0f * x);
  return (e - 1.0f) / (e + 1.0f);
}

// tagged publish: slot s entry = ((s+1)<<32) | f32bits(h). poison 0xAAAAAAAA never matches.
__device__ __forceinline__ void publish_h(u64* hx, int slot, int idx, float h) {
  h = finz(h);
  u64 v = ((u64)(unsigned)(slot + 1) << 32) | (u64)__float_as_uint(h);
  __hip_atomic_store(&hx[(size_t)slot * HID + idx], v,
                     __ATOMIC_RELAXED, __HIP_MEMORY_SCOPE_AGENT);
}

// poll 2 consecutive entries of slot for tag (slot+1); watchdog -> dead thread
__device__ __forceinline__ void poll2(const u64* hx, int slot, int j0,
                                      float* v, int* alive) {
  const u64* p = hx + (size_t)slot * HID + j0;
  const unsigned tag = (unsigned)(slot + 1);
  if (*alive) {
    int spins = 0;
    for (;;) {
      u64 a = __hip_atomic_load(&p[0], __ATOMIC_RELAXED, __HIP_MEMORY_SCOPE_AGENT);
      u64 b = __hip_atomic_load(&p[1], __ATOMIC_RELAXED, __HIP_MEMORY_SCOPE_AGENT);
      if ((unsigned)(a >> 32) == tag && (unsigned)(b >> 32) == tag) {
        v[0] = finz(__uint_as_float((unsigned)a));
        v[1] = finz(__uint_as_float((unsigned)b));
        return;
      }
      if (++spins > SPIN_MAX) { *alive = 0; break; }
      __builtin_amdgcn_s_sleep(1);
    }
  }
  v[0] = v[1] = 0.f;
}

// ---------------------------------------------------------------------------
// Phase 0: f32 -> bf16 conversion
// ---------------------------------------------------------------------------
__global__ __launch_bounds__(256) void cvt_bf16_k(const float* __restrict__ src,
                                                  u16* __restrict__ dst, int n4) {
  int i = blockIdx.x * 256 + threadIdx.x;
  if (i < n4) {
    float4 v = *(const float4*)(src + (size_t)i * 4);
    u16 o0 = f2bf(v.x), o1 = f2bf(v.y), o2 = f2bf(v.z), o3 = f2bf(v.w);
    ushort4 o = {o0, o1, o2, o3};
    *(ushort4*)(dst + (size_t)i * 4) = o;
  }
}

// ---------------------------------------------------------------------------
// Phase 1: xg = inp @ W_ih^T + b_ih (f32 out). 128x128 tile, BK=64, bf16 MFMA.
// ---------------------------------------------------------------------------
__global__ __launch_bounds__(256) void xg_gemm_k(const u16* __restrict__ A,      // [2048,4096] bf16
                                                 const u16* __restrict__ B,      // [4096,4096] bf16
                                                 const float* __restrict__ bias, // [4096] f32
                                                 float* __restrict__ C)          // [2048,4096] f32
{
  __shared__ __align__(16) u16 As[128 * 64];
  __shared__ __align__(16) u16 Bs[128 * 64];
  const int tid  = threadIdx.x;
  const int lane = tid & 63;
  const int quad = lane >> 4;
  const int l16  = lane & 15;
  const int wid  = tid >> 6;
  const int wm   = wid >> 1, wn = wid & 1;
  const int tileM = blockIdx.y * 128;
  const int tileN = blockIdx.x * 128;

  floatx4 acc[4][4];
  #pragma unroll
  for (int mi = 0; mi < 4; ++mi)
    #pragma unroll
    for (int ni = 0; ni < 4; ++ni)
      acc[mi][ni] = (floatx4){0.f, 0.f, 0.f, 0.f};

  for (int k0 = 0; k0 < K_IN; k0 += 64) {
    #pragma unroll
    for (int i = 0; i < 4; ++i) {
      int c = i * 256 + tid;
      int row = c >> 3, col = (c & 7) * 8;
      *(short8*)(As + c * 8) = *(const short8*)(A + (size_t)(tileM + row) * K_IN + k0 + col);
      *(short8*)(Bs + c * 8) = *(const short8*)(B + (size_t)(tileN + row) * K_IN + k0 + col);
    }
    __syncthreads();
    #pragma unroll
    for (int kk = 0; kk < 64; kk += 32) {
      short8 av[4], bv[4];
      #pragma unroll
      for (int mi = 0; mi < 4; ++mi)
        av[mi] = *(const short8*)(As + (wm * 64 + mi * 16 + l16) * 64 + kk + quad * 8);
      #pragma unroll
      for (int ni = 0; ni < 4; ++ni)
        bv[ni] = *(const short8*)(Bs + (wn * 64 + ni * 16 + l16) * 64 + kk + quad * 8);
      #pragma unroll
      for (int mi = 0; mi < 4; ++mi)
        #pragma unroll
        for (int ni = 0; ni < 4; ++ni)
          acc[mi][ni] = __builtin_amdgcn_mfma_f32_16x16x32_bf16(av[mi], bv[ni], acc[mi][ni], 0, 0, 0);
    }
    __syncthreads();
  }
  #pragma unroll
  for (int ni = 0; ni < 4; ++ni) {
    int n = tileN + wn * 64 + ni * 16 + l16;
    float bn = bias[n];
    #pragma unroll
    for (int mi = 0; mi < 4; ++mi) {
      int mbase = tileM + wm * 64 + mi * 16 + quad * 4;
      #pragma unroll
      for (int r = 0; r < 4; ++r)
        C[(size_t)(mbase + r) * G4H + n] = acc[mi][ni][r] + bn;
    }
  }
}

// ---------------------------------------------------------------------------
// Phase 2: persistent scan (R6 structure, widened to 512 threads = 8 waves).
// Block g owns units [8g, 8g+8). Wave w handles gate q=w>>1, units
// u = (w&1)*4 + i, i=0..3  (4 rows/wave -> 64 FMA/lane critical path).
// Each thread polls/stages only 2 tagged u64 entries (short detect sweep).
// ---------------------------------------------------------------------------
__global__ __launch_bounds__(512, 1) void lstm_scan_k(const float* __restrict__ Whh,
                                                      const float* __restrict__ bhh,
                                                      const float* __restrict__ h1,
                                                      const float* __restrict__ c1,
                                                      const float* __restrict__ fcw,
                                                      const float* __restrict__ fcb,
                                                      const float* __restrict__ xg,
                                                      u64* hx,        // [T_STEPS+1][1024]
                                                      float* out)     // [2080] f32
{
  const int g    = blockIdx.x;
  const int tid  = threadIdx.x;
  const int lane = tid & 63;
  const int w    = tid >> 6;           // wave 0..7
  const int q    = w >> 1;             // gate 0..3 (i,f,g,o)
  const int ub   = (w & 1) * 4;        // unit sub-block 0 or 4

  __shared__ float h_local[HID];
  __shared__ float gsum[32];           // [q*8 + u]
  __shared__ float xgb[2][32];         // parity double-buffer
  __shared__ float bhhb[32];
  __shared__ float pp[32][16];

  // W_hh rows for this wave's 4 dots -> VGPRs
  float wreg[4][16];
  #pragma unroll
  for (int i = 0; i < 4; ++i) {
    const size_t row = (size_t)(q * HID + g * 8 + ub + i);
    #pragma unroll
    for (int j = 0; j < 16; ++j)
      wreg[i][j] = Whh[row * HID + j * 64 + lane];
  }
  if (tid < 32) bhhb[tid] = bhh[(tid >> 3) * HID + g * 8 + (tid & 7)];

  float c_state = 0.f;
  if (tid < 8) {
    c_state = c1[g * 8 + tid];
    publish_h(hx, 0, g * 8 + tid, h1[g * 8 + tid]);
  }

  int alive = 1;
  const int j0 = tid * 2;              // 512 threads x 2 entries = 1024
  for (int t = 0; t < T_STEPS; ++t) {
    float xval = 0.f;                  // issue xg load before polling
    if (tid < 32) xval = finz(xg[(size_t)t * G4H + (tid >> 3) * HID + g * 8 + (tid & 7)]);
    float v[2];
    poll2(hx, t, j0, v, &alive);
    h_local[j0 + 0] = v[0]; h_local[j0 + 1] = v[1];
    if (tid < 32) xgb[t & 1][tid] = xval;
    __syncthreads();

    // 4 row-dots per wave; h_local reads lane-strided (2-way alias = free)
    float s[4] = {0.f, 0.f, 0.f, 0.f};
    #pragma unroll
    for (int j = 0; j < 16; ++j) {
      float hv = h_local[j * 64 + lane];
      #pragma unroll
      for (int i = 0; i < 4; ++i) s[i] = fmaf(wreg[i][j], hv, s[i]);
    }
    #pragma unroll
    for (int d = 1; d < 64; d <<= 1) {
      #pragma unroll
      for (int i = 0; i < 4; ++i) s[i] += __shfl_xor(s[i], d, 64);
    }
    if (lane == 0) {
      #pragma unroll
      for (int i = 0; i < 4; ++i) gsum[q * 8 + ub + i] = s[i];
    }
    __syncthreads();

    if (tid < 8) {
      const int u = tid;
      const float* xb = xgb[t & 1];
      float gi = gsum[u]      + xb[u]      + bhhb[u];
      float gf = gsum[8 + u]  + xb[8 + u]  + bhhb[8 + u];
      float gg = gsum[16 + u] + xb[16 + u] + bhhb[16 + u];
      float go = gsum[24 + u] + xb[24 + u] + bhhb[24 + u];
      float iv = sigm(gi), fv = sigm(gf), gv = tanh_s(gg), ov = sigm(go);
      c_state = finz(fv * c_state + iv * gv);
      float hval = ov * tanh_s(c_state);
      publish_h(hx, t + 1, g * 8 + u, hval);
      if (t == 1023) {                 // hs[STRIDE-1], cs[STRIDE-1]
        out[32 + g * 8 + u]       = finz(hval);
        out[32 + HID + g * 8 + u] = finz(c_state);
      }
    }
  }

  // out[0:32] = tanh(h_fin @ fc_w^T + fc_b): block 0 only
  if (g == 0) {
    float v[2];
    poll2(hx, T_STEPS, j0, v, &alive);
    h_local[j0 + 0] = v[0]; h_local[j0 + 1] = v[1];
    __syncthreads();
    const int m = tid >> 4, seg = tid & 15;   // 32 rows x 16 partials of 64
    float pacc = 0.f;
    for (int k = seg * 64; k < seg * 64 + 64; ++k)
      pacc = fmaf(fcw[m * HID + k], h_local[k], pacc);
    pp[m][seg] = finz(pacc);
    __syncthreads();
    if (tid < 32) {
      float sum = fcb[tid];
      #pragma unroll
      for (int i = 0; i < 16; ++i) sum += pp[tid][i];
      out[tid] = tanh_s(finz(sum));
    }
  }
}

extern "C" void kernel_launch(void* const* d_in, const int* in_sizes, int n_in,
                              void* d_out, int out_size, void* d_ws, size_t ws_size,
                              hipStream_t stream) {
  const float* inp = (const float*)d_in[0];
  const float* h1  = (const float*)d_in[1];
  const float* c1  = (const float*)d_in[2];
  const float* Wih = (const float*)d_in[3];
  const float* Whh = (const float*)d_in[4];
  const float* bih = (const float*)d_in[5];
  const float* bhh = (const float*)d_in[6];
  const float* fcw = (const float*)d_in[7];
  const float* fcb = (const float*)d_in[8];
  float* out = (float*)d_out;

  const size_t xg_bytes  = (size_t)T_STEPS * G4H * 4;             // 33.5 MB
  const size_t hx_bytes  = (size_t)(T_STEPS + 1) * HID * 8;       // 16.8 MB
  const size_t ab_bytes  = (size_t)T_STEPS * K_IN * 2;            // 16.8 MB
  const size_t wb_bytes  = (size_t)G4H * K_IN * 2;                // 33.5 MB
  if (ws_size < xg_bytes + hx_bytes + ab_bytes + wb_bytes) return;

  float* xg   = (float*)d_ws;
  u64*   hx   = (u64*)((char*)d_ws + xg_bytes);
  u16*   Abf  = (u16*)((char*)d_ws + xg_bytes + hx_bytes);
  u16*   Wbf  = (u16*)((char*)d_ws + xg_bytes + hx_bytes + ab_bytes);

  const int nA4 = T_STEPS * K_IN / 4;
  const int nW4 = G4H * K_IN / 4;
  cvt_bf16_k<<<dim3((nA4 + 255) / 256), 256, 0, stream>>>(inp, Abf, nA4);
  cvt_bf16_k<<<dim3((nW4 + 255) / 256), 256, 0, stream>>>(Wih, Wbf, nW4);
  xg_gemm_k<<<dim3(G4H / 128, T_STEPS / 128), 256, 0, stream>>>(Abf, Wbf, bih, xg);
  lstm_scan_k<<<dim3(NWG), 512, 0, stream>>>(Whh, bhh, h1, c1, fcw, fcb, xg, hx, out);
}